// Round 1
// baseline (1007.340 us; speedup 1.0000x reference)
//
#include <hip/hip_runtime.h>

#define B_ 128
#define T_ 1024
#define D_ 128
#define H_ 128

typedef short bf16x8 __attribute__((ext_vector_type(8)));
typedef float f32x4 __attribute__((ext_vector_type(4)));

// round-to-nearest-even f32 -> bf16 (finite inputs only)
__device__ inline short f2bf(float f) {
    union { float f; unsigned u; } v; v.f = f;
    unsigned u = v.u;
    unsigned r = (u + 0x7fffu + ((u >> 16) & 1u)) >> 16;
    return (short)r;
}

// tanh(x) = 1 - 2/(1+e^{2x}); robust at +-inf of exp
__device__ inline float fast_tanh(float x) {
    float e = __expf(2.0f * x);
    return 1.0f - __fdividef(2.0f, 1.0f + e);
}

// ---------------------------------------------------------------------------
// Kernel 1: xu = x @ U + bu  ->  written into out[B][T][H] (f32).
// Rows = flattened (b,t), 131072 rows x 128 cols, K=128. bf16 MFMA 16x16x32.
// Block = 256 threads (4 waves), each wave: 16 rows x 128 cols.
// U staged once per block into LDS in B-fragment-packed layout.
// ---------------------------------------------------------------------------
__global__ __launch_bounds__(256) void xu_kernel(
    const float* __restrict__ x, const float* __restrict__ U,
    const float* __restrict__ bu, float* __restrict__ out)
{
    __shared__ bf16x8 uf[2048];  // [nt(8)][kk(4)][lane(64)] B-fragments of U
    const int tid  = threadIdx.x;
    const int lane = tid & 63;
    const int wave = tid >> 6;
    const int q = lane >> 4, c = lane & 15;

    // Stage U fragments: slot s -> B[k=32kk+8q+j][n=16nt+c]
    for (int s = tid; s < 2048; s += 256) {
        int l = s & 63, kk = (s >> 6) & 3, nt = s >> 8;
        int lq = l >> 4, lc = l & 15;
        int kbase = 32 * kk + 8 * lq;
        int col = 16 * nt + lc;
        bf16x8 f;
#pragma unroll
        for (int j = 0; j < 8; ++j)
            f[j] = f2bf(U[(kbase + j) * H_ + col]);
        uf[s] = f;
    }

    // A-fragments: x rows (16 per wave), A[m=lane&15][k=32kk+8q+j]
    const int row0 = blockIdx.x * 64 + wave * 16;
    bf16x8 af[4];
#pragma unroll
    for (int kk = 0; kk < 4; ++kk) {
        const float* px = x + (row0 + (lane & 15)) * D_ + 32 * kk + 8 * q;
        f32x4 a0 = *(const f32x4*)px;
        f32x4 a1 = *(const f32x4*)(px + 4);
        bf16x8 f;
        f[0] = f2bf(a0[0]); f[1] = f2bf(a0[1]); f[2] = f2bf(a0[2]); f[3] = f2bf(a0[3]);
        f[4] = f2bf(a1[0]); f[5] = f2bf(a1[1]); f[6] = f2bf(a1[2]); f[7] = f2bf(a1[3]);
        af[kk] = f;
    }
    __syncthreads();

#pragma unroll
    for (int nt = 0; nt < 8; ++nt) {
        float bub = bu[16 * nt + c];
        f32x4 acc = {bub, bub, bub, bub};
#pragma unroll
        for (int kk = 0; kk < 4; ++kk)
            acc = __builtin_amdgcn_mfma_f32_16x16x32_bf16(af[kk], uf[(nt * 4 + kk) * 64 + lane], acc, 0, 0, 0);
        // C/D layout: col = lane&15, row = 4q + reg
        float* po = out + (row0 + 4 * q) * H_ + 16 * nt + c;
#pragma unroll
        for (int r = 0; r < 4; ++r)
            po[r * H_] = acc[r];
    }
}

// ---------------------------------------------------------------------------
// Kernel 2: sequential scan. Grid = 8 blocks (16 batch rows each) x 1024 thr.
// Waves 0..7  (h-waves): st_t = tanh(xu_t + st_{t-1}@W + bw), write LDS slot.
// Waves 8..15 (o-waves): o_{t-1} = tanh(st_{t-1}@V + bv), store to out.
// xu lives in out[B][T][H] (written by kernel 1); o overwrites it in place,
// always at column t-1 while reads (prefetch) are at column t+1.
// One __syncthreads per step. Weight B-fragments held in registers for all t.
// ---------------------------------------------------------------------------
__global__ __launch_bounds__(1024) void scan_kernel(
    float* __restrict__ out,
    const float* __restrict__ h0,
    const float* __restrict__ W, const float* __restrict__ V,
    const float* __restrict__ bw, const float* __restrict__ bv)
{
    // st slots: [parity][m=16][k=128 + 8 pad] bf16. st_t lives in slot[t&1];
    // h0 = st_{-1} in slot[1]. Row pad 8 -> 272B stride: 2-way bank alias (free).
    __shared__ __align__(16) short st[2][16][136];

    const int tid  = threadIdx.x;
    const int lane = tid & 63;
    const int wave = tid >> 6;
    const bool is_h = wave < 8;
    const int n  = wave & 7;
    const int q = lane >> 4, c = lane & 15;
    const int c0 = 16 * n;
    const int b0 = blockIdx.x * 16;

    // Weight B-fragments (held for all 1024 steps): B[k=32kk+8q+j][n=c0+c]
    const float* M = is_h ? W : V;
    bf16x8 wf[4];
#pragma unroll
    for (int kk = 0; kk < 4; ++kk) {
        int kbase = 32 * kk + 8 * q;
        bf16x8 f;
#pragma unroll
        for (int j = 0; j < 8; ++j)
            f[j] = f2bf(M[(kbase + j) * H_ + c0 + c]);
        wf[kk] = f;
    }
    const float vbias = is_h ? bw[c0 + c] : bv[c0 + c];

    // Stage h0 -> slot[1]: 16 waves x 1 row, 2 values/lane, packed b32 write
    {
        int m = wave;
        int k0 = lane * 2;
        const float* ph = h0 + (b0 + m) * H_ + k0;
        float2 hv = *(const float2*)ph;
        union { short s2[2]; unsigned u; } pk;
        pk.s2[0] = f2bf(hv.x);
        pk.s2[1] = f2bf(hv.y);
        *(unsigned*)&st[1][m][k0] = pk.u;
    }

    // per-lane base into out for rows b0+4q+r, col c0+c
    const int obase = (b0 + 4 * q) * T_ * H_ + c0 + c;

    // prefetch xu_0 (h-waves)
    f32x4 xupre = {0.f, 0.f, 0.f, 0.f};
    if (is_h) {
#pragma unroll
        for (int r = 0; r < 4; ++r)
            xupre[r] = out[obase + r * T_ * H_];
    }
    __syncthreads();

    for (int t = 0; t < T_; ++t) {
        const int pr = (t + 1) & 1;  // slot holding st_{t-1}
        const int pw = t & 1;        // slot to write st_t

        if (is_h) {
            f32x4 xu_c = xupre;
            if (t + 1 < T_) {  // prefetch xu_{t+1}
#pragma unroll
                for (int r = 0; r < 4; ++r)
                    xupre[r] = out[obase + r * T_ * H_ + (t + 1) * H_];
            }
            bf16x8 af[4];
#pragma unroll
            for (int kk = 0; kk < 4; ++kk)
                af[kk] = *(const bf16x8*)&st[pr][lane & 15][32 * kk + 8 * q];
            f32x4 accA, accB;
#pragma unroll
            for (int r = 0; r < 4; ++r) { accA[r] = xu_c[r] + vbias; accB[r] = 0.f; }
            // two independent K-chains to halve MFMA dependency latency
            accA = __builtin_amdgcn_mfma_f32_16x16x32_bf16(af[0], wf[0], accA, 0, 0, 0);
            accB = __builtin_amdgcn_mfma_f32_16x16x32_bf16(af[1], wf[1], accB, 0, 0, 0);
            accA = __builtin_amdgcn_mfma_f32_16x16x32_bf16(af[2], wf[2], accA, 0, 0, 0);
            accB = __builtin_amdgcn_mfma_f32_16x16x32_bf16(af[3], wf[3], accB, 0, 0, 0);
#pragma unroll
            for (int r = 0; r < 4; ++r) {
                float s = fast_tanh(accA[r] + accB[r]);
                st[pw][4 * q + r][c0 + c] = f2bf(s);
            }
        } else if (t > 0) {
            bf16x8 af[4];
#pragma unroll
            for (int kk = 0; kk < 4; ++kk)
                af[kk] = *(const bf16x8*)&st[pr][lane & 15][32 * kk + 8 * q];
            f32x4 acc = {vbias, vbias, vbias, vbias};
#pragma unroll
            for (int kk = 0; kk < 4; ++kk)
                acc = __builtin_amdgcn_mfma_f32_16x16x32_bf16(af[kk], wf[kk], acc, 0, 0, 0);
#pragma unroll
            for (int r = 0; r < 4; ++r)
                out[obase + r * T_ * H_ + (t - 1) * H_] = fast_tanh(acc[r]);
        }
        __syncthreads();
    }

    // epilogue: o_{T-1} from slot[(T-1)&1] = slot[1]
    if (!is_h) {
        bf16x8 af[4];
#pragma unroll
        for (int kk = 0; kk < 4; ++kk)
            af[kk] = *(const bf16x8*)&st[1][lane & 15][32 * kk + 8 * q];
        f32x4 acc = {vbias, vbias, vbias, vbias};
#pragma unroll
        for (int kk = 0; kk < 4; ++kk)
            acc = __builtin_amdgcn_mfma_f32_16x16x32_bf16(af[kk], wf[kk], acc, 0, 0, 0);
#pragma unroll
        for (int r = 0; r < 4; ++r)
            out[obase + r * T_ * H_ + (T_ - 1) * H_] = fast_tanh(acc[r]);
    }
}

extern "C" void kernel_launch(void* const* d_in, const int* in_sizes, int n_in,
                              void* d_out, int out_size, void* d_ws, size_t ws_size,
                              hipStream_t stream) {
    const float* x  = (const float*)d_in[0];
    const float* h0 = (const float*)d_in[1];
    const float* U  = (const float*)d_in[2];
    const float* W  = (const float*)d_in[3];
    const float* V  = (const float*)d_in[4];
    const float* bu = (const float*)d_in[5];
    const float* bw = (const float*)d_in[6];
    const float* bv = (const float*)d_in[7];
    float* out = (float*)d_out;

    // xu = x@U + bu into out[B][T][H]
    xu_kernel<<<2048, 256, 0, stream>>>(x, U, bu, out);
    // sequential scan, in-place xu -> o
    scan_kernel<<<8, 1024, 0, stream>>>(out, h0, W, V, bw, bv);
}

// Round 2
// 896.024 us; speedup vs baseline: 1.1242x; 1.1242x over previous
//
#include <hip/hip_runtime.h>

#define B_ 128
#define T_ 1024
#define D_ 128
#define H_ 128

typedef short bf16x8 __attribute__((ext_vector_type(8)));
typedef float f32x4 __attribute__((ext_vector_type(4)));

// round-to-nearest-even f32 -> bf16 (finite inputs only)
__device__ inline short f2bf(float f) {
    union { float f; unsigned u; } v; v.f = f;
    unsigned u = v.u;
    unsigned r = (u + 0x7fffu + ((u >> 16) & 1u)) >> 16;
    return (short)r;
}

// tanh(x) = 1 - 2/(1+e^{2x}); robust at +-inf of exp
__device__ inline float fast_tanh(float x) {
    float e = __expf(2.0f * x);
    return 1.0f - __fdividef(2.0f, 1.0f + e);
}

// Workgroup barrier that drains ONLY LDS (lgkmcnt), not VMEM (vmcnt).
// __syncthreads() emits s_waitcnt vmcnt(0) before s_barrier, which would put
// every in-flight global prefetch/store on the per-step critical path. The
// cross-wave dependency in the scan is LDS-only (st slots); global xu reads
// (plane t+8) and o writes (plane t-1) never alias across a barrier window.
__device__ inline void lds_barrier() {
    asm volatile("s_waitcnt lgkmcnt(0)\n\ts_barrier" ::: "memory");
}

// ---------------------------------------------------------------------------
// Kernel 1: xu = x @ U + bu  ->  out[B][T][H] (f32).
// 512 blocks x 256 thr; each block stages U-fragments into LDS once, then
// processes 4 row-tiles of 64 rows (staging amortized 4x vs round-1).
// ---------------------------------------------------------------------------
__global__ __launch_bounds__(256) void xu_kernel(
    const float* __restrict__ x, const float* __restrict__ U,
    const float* __restrict__ bu, float* __restrict__ out)
{
    __shared__ bf16x8 uf[2048];  // [nt(8)][kk(4)][lane(64)] B-fragments of U
    const int tid  = threadIdx.x;
    const int lane = tid & 63;
    const int wave = tid >> 6;
    const int q = lane >> 4, c = lane & 15;

    // Stage U fragments: slot s -> B[k=32kk+8q+j][n=16nt+c]
    for (int s = tid; s < 2048; s += 256) {
        int l = s & 63, kk = (s >> 6) & 3, nt = s >> 8;
        int lq = l >> 4, lc = l & 15;
        int kbase = 32 * kk + 8 * lq;
        int col = 16 * nt + lc;
        bf16x8 f;
#pragma unroll
        for (int j = 0; j < 8; ++j)
            f[j] = f2bf(U[(kbase + j) * H_ + col]);
        uf[s] = f;
    }

    // per-lane bias values, hoisted out of the tile loop
    float bub[8];
#pragma unroll
    for (int nt = 0; nt < 8; ++nt) bub[nt] = bu[16 * nt + c];

    __syncthreads();

    for (int it = 0; it < 4; ++it) {
        const int row0 = (blockIdx.x * 4 + it) * 64 + wave * 16;

        // A-fragments: A[m=lane&15][k=32kk+8q+j]
        bf16x8 af[4];
#pragma unroll
        for (int kk = 0; kk < 4; ++kk) {
            const float* px = x + (row0 + (lane & 15)) * D_ + 32 * kk + 8 * q;
            f32x4 a0 = *(const f32x4*)px;
            f32x4 a1 = *(const f32x4*)(px + 4);
            bf16x8 f;
            f[0] = f2bf(a0[0]); f[1] = f2bf(a0[1]); f[2] = f2bf(a0[2]); f[3] = f2bf(a0[3]);
            f[4] = f2bf(a1[0]); f[5] = f2bf(a1[1]); f[6] = f2bf(a1[2]); f[7] = f2bf(a1[3]);
            af[kk] = f;
        }

#pragma unroll
        for (int nt = 0; nt < 8; ++nt) {
            f32x4 acc = {bub[nt], bub[nt], bub[nt], bub[nt]};
#pragma unroll
            for (int kk = 0; kk < 4; ++kk)
                acc = __builtin_amdgcn_mfma_f32_16x16x32_bf16(af[kk], uf[(nt * 4 + kk) * 64 + lane], acc, 0, 0, 0);
            // C/D layout: col = lane&15, row = 4q + reg
            float* po = out + (row0 + 4 * q) * H_ + 16 * nt + c;
#pragma unroll
            for (int r = 0; r < 4; ++r)
                po[r * H_] = acc[r];
        }
    }
}

// ---------------------------------------------------------------------------
// Kernel 2: sequential scan. Grid = 8 blocks (16 batch rows each) x 1024 thr.
// Waves 0..7  (h-waves): st_t = tanh(xu_t + st_{t-1}@W + bw) -> LDS slot.
// Waves 8..15 (o-waves): o_{t-1} = tanh(st_{t-1}@V + bv) -> out (1 behind).
// xu lives in out[B][T][H] (written by kernel 1); o overwrites plane t-1
// while xu reads run at plane t+8 (8-deep register FIFO, loop unrolled x8).
// lds_barrier (lgkm-only) keeps all VMEM off the per-step critical path.
// ---------------------------------------------------------------------------
__global__ __launch_bounds__(1024) void scan_kernel(
    float* __restrict__ out,
    const float* __restrict__ h0,
    const float* __restrict__ W, const float* __restrict__ V,
    const float* __restrict__ bw, const float* __restrict__ bv)
{
    // st slots: [parity][m=16][k=128 + 8 pad] bf16. st_t -> slot[t&1];
    // h0 = st_{-1} -> slot[1]. Row pad 8 -> 272B stride (2-way alias, free).
    __shared__ __align__(16) short st[2][16][136];

    const int tid  = threadIdx.x;
    const int lane = tid & 63;
    const int wave = tid >> 6;
    const bool is_h = wave < 8;
    const int n  = wave & 7;
    const int q = lane >> 4, c = lane & 15;
    const int c0 = 16 * n;
    const int b0 = blockIdx.x * 16;

    // Weight B-fragments (held in regs all 1024 steps): B[k=32kk+8q+j][n=c0+c]
    const float* M = is_h ? W : V;
    bf16x8 wf[4];
#pragma unroll
    for (int kk = 0; kk < 4; ++kk) {
        int kbase = 32 * kk + 8 * q;
        bf16x8 f;
#pragma unroll
        for (int j = 0; j < 8; ++j)
            f[j] = f2bf(M[(kbase + j) * H_ + c0 + c]);
        wf[kk] = f;
    }
    const float vbias = is_h ? bw[c0 + c] : bv[c0 + c];

    // Stage h0 -> slot[1]: 16 waves x 1 row, 2 values/lane, packed b32 write
    {
        int m = wave;
        int k0 = lane * 2;
        const float* ph = h0 + (b0 + m) * H_ + k0;
        float2 hv = *(const float2*)ph;
        union { short s2[2]; unsigned u; } pk;
        pk.s2[0] = f2bf(hv.x);
        pk.s2[1] = f2bf(hv.y);
        *(unsigned*)&st[1][m][k0] = pk.u;
    }

    // per-lane base into out for rows b0+4q+r, col c0+c
    const int obase = (b0 + 4 * q) * T_ * H_ + c0 + c;

    // 8-deep xu prefetch FIFO (h-waves): slot u holds plane t with t%8==u
    f32x4 xubuf[8];
    if (is_h) {
#pragma unroll
        for (int u = 0; u < 8; ++u)
#pragma unroll
            for (int r = 0; r < 4; ++r)
                xubuf[u][r] = out[obase + r * T_ * H_ + u * H_];
    }
    lds_barrier();

    for (int tb = 0; tb < T_ / 8; ++tb) {
#pragma unroll
        for (int u = 0; u < 8; ++u) {
            const int t = tb * 8 + u;
            const int pr = (u + 1) & 1;  // slot holding st_{t-1}
            const int pw = u & 1;        // slot to write st_t

            if (is_h) {
                f32x4 xu_c = xubuf[u];
                if (t + 8 < T_) {  // refill FIFO slot with plane t+8
#pragma unroll
                    for (int r = 0; r < 4; ++r)
                        xubuf[u][r] = out[obase + r * T_ * H_ + (t + 8) * H_];
                }
                bf16x8 af[4];
#pragma unroll
                for (int kk = 0; kk < 4; ++kk)
                    af[kk] = *(const bf16x8*)&st[pr][lane & 15][32 * kk + 8 * q];
                f32x4 accA, accB;
#pragma unroll
                for (int r = 0; r < 4; ++r) { accA[r] = xu_c[r] + vbias; accB[r] = 0.f; }
                // two independent K-chains to halve MFMA dependency latency
                accA = __builtin_amdgcn_mfma_f32_16x16x32_bf16(af[0], wf[0], accA, 0, 0, 0);
                accB = __builtin_amdgcn_mfma_f32_16x16x32_bf16(af[1], wf[1], accB, 0, 0, 0);
                accA = __builtin_amdgcn_mfma_f32_16x16x32_bf16(af[2], wf[2], accA, 0, 0, 0);
                accB = __builtin_amdgcn_mfma_f32_16x16x32_bf16(af[3], wf[3], accB, 0, 0, 0);
#pragma unroll
                for (int r = 0; r < 4; ++r) {
                    float s = fast_tanh(accA[r] + accB[r]);
                    st[pw][4 * q + r][c0 + c] = f2bf(s);
                }
            } else if (t > 0) {
                bf16x8 af[4];
#pragma unroll
                for (int kk = 0; kk < 4; ++kk)
                    af[kk] = *(const bf16x8*)&st[pr][lane & 15][32 * kk + 8 * q];
                f32x4 acc = {vbias, vbias, vbias, vbias};
#pragma unroll
                for (int kk = 0; kk < 4; ++kk)
                    acc = __builtin_amdgcn_mfma_f32_16x16x32_bf16(af[kk], wf[kk], acc, 0, 0, 0);
#pragma unroll
                for (int r = 0; r < 4; ++r)
                    out[obase + r * T_ * H_ + (t - 1) * H_] = fast_tanh(acc[r]);
            }
            lds_barrier();
        }
    }

    // epilogue: o_{T-1} from slot[(T-1)&1] = slot[1]
    if (!is_h) {
        bf16x8 af[4];
#pragma unroll
        for (int kk = 0; kk < 4; ++kk)
            af[kk] = *(const bf16x8*)&st[1][lane & 15][32 * kk + 8 * q];
        f32x4 acc = {vbias, vbias, vbias, vbias};
#pragma unroll
        for (int kk = 0; kk < 4; ++kk)
            acc = __builtin_amdgcn_mfma_f32_16x16x32_bf16(af[kk], wf[kk], acc, 0, 0, 0);
#pragma unroll
        for (int r = 0; r < 4; ++r)
            out[obase + r * T_ * H_ + (T_ - 1) * H_] = fast_tanh(acc[r]);
    }
}

extern "C" void kernel_launch(void* const* d_in, const int* in_sizes, int n_in,
                              void* d_out, int out_size, void* d_ws, size_t ws_size,
                              hipStream_t stream) {
    const float* x  = (const float*)d_in[0];
    const float* h0 = (const float*)d_in[1];
    const float* U  = (const float*)d_in[2];
    const float* W  = (const float*)d_in[3];
    const float* V  = (const float*)d_in[4];
    const float* bu = (const float*)d_in[5];
    const float* bw = (const float*)d_in[6];
    const float* bv = (const float*)d_in[7];
    float* out = (float*)d_out;

    // xu = x@U + bu into out[B][T][H]
    xu_kernel<<<512, 256, 0, stream>>>(x, U, bu, out);
    // sequential scan, in-place xu -> o
    scan_kernel<<<8, 1024, 0, stream>>>(out, h0, W, V, bw, bv);
}